// Round 4
// baseline (16.726 us; speedup 1.0000x reference)
//
#include <hip/hip_runtime.h>
#include <math.h>

// MMLU Llama head: RMSNorm(last token) -> 4-row GEMV -> softmax(4).
// Only x[last] and 4 rows of head_weight are live (~96 KB). Single-block
// latency-bound kernel at the graph-replay launch floor.
//
// R4 = R2's balanced body (ss spread across ALL 16 waves so barrier arrival
// is even; R3's group-0-only ss lengthened the critical path) + R3's
// parallel wave-0 tail (shuffle combine, 4 parallel expf) replacing the
// serial thread-0 tail. Fixed reduction order -> deterministic.

constexpr int D_MODEL = 4096;
constexpr int SEQ     = 2048;
constexpr int NOPT    = 4;

__global__ __launch_bounds__(1024) void mmlu_head_kernel(
    const float* __restrict__ x,        // [SEQ, D_MODEL]
    const float* __restrict__ nw,       // [D_MODEL]
    const float* __restrict__ hw,       // [VOCAB, D_MODEL]
    const int*   __restrict__ opt,      // [NOPT]
    float*       __restrict__ out)      // [NOPT]
{
    __shared__ float s_dot[16];         // per-wave dot partials (option = wid>>2)
    __shared__ float s_ss[16];          // per-wave sumsq partials

    const int tid  = threadIdx.x;       // 0..1023
    const int lane = tid & 63;
    const int wid  = tid >> 6;          // 0..15
    const int g    = tid >> 8;          // option 0..3 (wave-uniform)
    const int gt   = tid & 255;         // thread within option group

    // Load option index first (wave-uniform -> s_load) so the dependent
    // head-row loads issue as early as possible.
    const int row = opt[g];
    const float4* h4 = reinterpret_cast<const float4*>(hw + (size_t)row * D_MODEL);
    const float4* x4 = reinterpret_cast<const float4*>(x + (size_t)(SEQ - 1) * D_MODEL);
    const float4* w4 = reinterpret_cast<const float4*>(nw);

    // dot_g = sum_d hw[row][d] * x[d] * nw[d]
    float dot = 0.f;
    #pragma unroll
    for (int it = 0; it < 4; ++it) {
        int i = gt + it * 256;          // group covers all 1024 float4
        float4 a  = h4[i];
        float4 xv = x4[i];
        float4 wv = w4[i];
        dot += a.x * xv.x * wv.x + a.y * xv.y * wv.y
             + a.z * xv.z * wv.z + a.w * xv.w * wv.w;
    }

    // sum of squares, balanced across all 16 waves (one float4 per thread)
    float4 v = x4[tid];
    float ss = v.x * v.x + v.y * v.y + v.z * v.z + v.w * v.w;

    // interleaved wave reductions
    #pragma unroll
    for (int o = 32; o > 0; o >>= 1) {
        dot += __shfl_down(dot, o, 64);
        ss  += __shfl_down(ss,  o, 64);
    }
    if (lane == 0) {
        s_dot[wid] = dot;
        s_ss[wid]  = ss;
    }
    __syncthreads();
    if (wid != 0) return;

    // ---- wave-0 parallel tail ----
    // lanes 0..15: dot partials (option = lane>>2); lanes 16..31: ss partials.
    float pv = 0.f;
    if (lane < 16)      pv = s_dot[lane];
    else if (lane < 32) pv = s_ss[lane - 16];
    // sum groups of 4: lanes {0,4,8,12} hold option dots; {16,20,24,28} ss quarters
    pv += __shfl_xor(pv, 1, 64);
    pv += __shfl_xor(pv, 2, 64);
    float ssum = __shfl(pv, 16, 64) + __shfl(pv, 20, 64)
               + __shfl(pv, 24, 64) + __shfl(pv, 28, 64);
    const float rms = rsqrtf(ssum / (float)D_MODEL + 1e-5f);

    if (lane < 16 && (lane & 3) == 0) {
        float logit = pv * rms;
        float mx = fmaxf(logit, __shfl_xor(logit, 4, 64));
        mx = fmaxf(mx, __shfl_xor(mx, 8, 64));
        float e = expf(logit - mx);
        float denom = e + __shfl_xor(e, 4, 64);
        denom += __shfl_xor(denom, 8, 64);
        out[lane >> 2] = e / denom;
    }
}

extern "C" void kernel_launch(void* const* d_in, const int* in_sizes, int n_in,
                              void* d_out, int out_size, void* d_ws, size_t ws_size,
                              hipStream_t stream) {
    const float* x   = (const float*)d_in[0];   // [2048, 4096] f32
    const float* nw  = (const float*)d_in[1];   // [4096] f32
    const float* hw  = (const float*)d_in[2];   // [128256, 4096] f32
    const int*   opt = (const int*)d_in[3];     // [4] i32
    float* out = (float*)d_out;                 // [4] f32

    mmlu_head_kernel<<<1, 1024, 0, stream>>>(x, nw, hw, opt, out);
}

// Round 5
// 9.603 us; speedup vs baseline: 1.7417x; 1.7417x over previous
//
#include <hip/hip_runtime.h>
#include <math.h>

// MMLU Llama head: RMSNorm(last token) -> 4-row GEMV -> softmax(4).
// Only the last token's row of x and the 4 option rows of head_weight are
// live; everything else in the reference is dead work. ~96 KB total traffic,
// single-block latency-bound kernel.
//
// R5 == R2 verbatim (best-measured: 9.27 us). R3/R4 perturbations landed at
// 11.1/16.7 us -- inside the harness's launch/replay noise band; the kernel
// body itself is <1 us of work. Structure: ONE barrier; sumsq and the 4
// head-row dots are independent (rms applied as a scalar post-reduction);
// opt[] loaded first (wave-uniform -> s_load) so head-row loads issue early;
// ss work balanced across all 16 waves for even barrier arrival.

constexpr int D_MODEL = 4096;
constexpr int SEQ     = 2048;
constexpr int NOPT    = 4;

__global__ __launch_bounds__(1024) void mmlu_head_kernel(
    const float* __restrict__ x,        // [SEQ, D_MODEL]
    const float* __restrict__ nw,       // [D_MODEL]
    const float* __restrict__ hw,       // [VOCAB, D_MODEL]
    const int*   __restrict__ opt,      // [NOPT]
    float*       __restrict__ out)      // [NOPT]
{
    __shared__ float s_red[16];         // per-wave sumsq partials
    __shared__ float s_dot[NOPT][4];    // per-option per-wave dot partials

    const int tid  = threadIdx.x;       // 0..1023
    const int lane = tid & 63;
    const int wid  = tid >> 6;          // 0..15
    const int g    = tid >> 8;          // option 0..3 (wave-uniform)
    const int gt   = tid & 255;         // thread within option group

    // Issue the option index load FIRST (wave-uniform -> scalar load), so the
    // dependent head-row loads start as early as possible.
    const int row = opt[g];
    const float4* h4 = reinterpret_cast<const float4*>(hw + (size_t)row * D_MODEL);

    const float4* x4 = reinterpret_cast<const float4*>(x + (size_t)(SEQ - 1) * D_MODEL);
    const float4* w4 = reinterpret_cast<const float4*>(nw);

    // ---- head-row dot partial: dot_g = sum_d hw[row][d] * x[d] * nw[d] ----
    float dot = 0.f;
    #pragma unroll
    for (int it = 0; it < 4; ++it) {
        int i = gt + it * 256;          // covers 1024 float4 per option
        float4 a  = h4[i];
        float4 xv = x4[i];
        float4 wv = w4[i];
        dot += a.x * xv.x * wv.x + a.y * xv.y * wv.y
             + a.z * xv.z * wv.z + a.w * xv.w * wv.w;
    }

    // ---- sum of squares of last-token row (independent of dot) ----
    float4 v = x4[tid];
    float ss = v.x * v.x + v.y * v.y + v.z * v.z + v.w * v.w;

    // ---- interleaved wave reductions ----
    #pragma unroll
    for (int o = 32; o > 0; o >>= 1) {
        ss  += __shfl_down(ss,  o, 64);
        dot += __shfl_down(dot, o, 64);
    }
    if (lane == 0) {
        s_red[wid] = ss;
        s_dot[g][wid & 3] = dot;
    }
    __syncthreads();

    // ---- final combine + softmax over 4 logits (thread 0) ----
    if (tid == 0) {
        float t = 0.f;
        #pragma unroll
        for (int i = 0; i < 16; ++i) t += s_red[i];
        const float rms = rsqrtf(t / (float)D_MODEL + 1e-5f);

        float logits[NOPT];
        float mx = -1e30f;
        #pragma unroll
        for (int k = 0; k < NOPT; ++k) {
            float d = (s_dot[k][0] + s_dot[k][1] + s_dot[k][2] + s_dot[k][3]) * rms;
            logits[k] = d;
            mx = fmaxf(mx, d);
        }
        float e[NOPT];
        float denom = 0.f;
        #pragma unroll
        for (int k = 0; k < NOPT; ++k) { e[k] = expf(logits[k] - mx); denom += e[k]; }
        #pragma unroll
        for (int k = 0; k < NOPT; ++k) out[k] = e[k] / denom;
    }
}

extern "C" void kernel_launch(void* const* d_in, const int* in_sizes, int n_in,
                              void* d_out, int out_size, void* d_ws, size_t ws_size,
                              hipStream_t stream) {
    const float* x   = (const float*)d_in[0];   // [2048, 4096] f32
    const float* nw  = (const float*)d_in[1];   // [4096] f32
    const float* hw  = (const float*)d_in[2];   // [128256, 4096] f32
    const int*   opt = (const int*)d_in[3];     // [4] i32
    float* out = (float*)d_out;                 // [4] f32

    mmlu_head_kernel<<<1, 1024, 0, stream>>>(x, nw, hw, opt, out);
}